// Round 9
// baseline (369.077 us; speedup 1.0000x reference)
//
#include <hip/hip_runtime.h>

#define GAS __attribute__((address_space(1)))
#define LAS __attribute__((address_space(3)))

typedef __attribute__((ext_vector_type(8))) short short8;
typedef __attribute__((ext_vector_type(4))) float f32x4;
typedef __attribute__((ext_vector_type(16))) float f32x16;
typedef __attribute__((ext_vector_type(4))) unsigned int u32x4;

#define MFMA16(a,b,c) __builtin_amdgcn_mfma_f32_16x16x32_bf16(a,b,c,0,0,0)
#define MFMA32(a,b,c) __builtin_amdgcn_mfma_f32_32x32x16_bf16(a,b,c,0,0,0)

// ---------- bf16 helpers ----------
__device__ __forceinline__ unsigned short f2b(float f) {
  unsigned u = __float_as_uint(f);
  u += 0x7fffu + ((u >> 16) & 1u);          // RNE
  return (unsigned short)(u >> 16);
}
__device__ __forceinline__ float b2f(unsigned short h) {
  return __uint_as_float(((unsigned)h) << 16);
}
__device__ __forceinline__ unsigned cvtpk(float a, float b) {
  unsigned r;
  asm("v_cvt_pk_bf16_f32 %0, %1, %2" : "=v"(r) : "v"(a), "v"(b));
  return r;
}
__device__ __forceinline__ void pl32swap(unsigned &x, unsigned &y) {
  auto r = __builtin_amdgcn_permlane32_swap((int)x, (int)y, false, false);
  x = (unsigned)r[0]; y = (unsigned)r[1];
}
__device__ __forceinline__ float xhalf_sum(float v) {
  auto r = __builtin_amdgcn_permlane32_swap(__float_as_int(v), __float_as_int(v), false, false);
  return __int_as_float(r[0]) + __int_as_float(r[1]);
}
__device__ __forceinline__ float fexp2(float x) {
  float r;
  asm("v_exp_f32 %0, %1" : "=v"(r) : "v"(x));   // D = 2^S0
  return r;
}
__device__ __forceinline__ short8 ld8(const unsigned short* p) {
  return *reinterpret_cast<const short8*>(p);
}

union FW { u32x4 u; short8 s; };

// ---------- fused fp32 -> bf16 convert (x + weights) + top-3 mask indices ----------
__global__ void cvt_topk(const float* __restrict__ x,
                         const float* __restrict__ Wq, const float* __restrict__ Wk,
                         const float* __restrict__ Wv, const float* __restrict__ Wo,
                         const float* __restrict__ band,
                         unsigned short* __restrict__ xb,
                         unsigned short* __restrict__ Wqkvb,
                         unsigned short* __restrict__ Wob,
                         int* __restrict__ idxout) {
  const int bid = blockIdx.x;
  if (bid < 12288) {
    const float* src;
    unsigned short* dst;
    int idx;
    if (bid < 8192) {                     // x: 2097152 float4
      src = x; dst = xb; idx = bid * 256 + threadIdx.x;
    } else {                              // weights: 4 x 262144 float4
      int wb = bid - 8192;
      int seg = wb >> 10;
      idx = (wb & 1023) * 256 + threadIdx.x;
      src = (seg == 0) ? Wq : (seg == 1) ? Wk : (seg == 2) ? Wv : Wo;
      dst = (seg == 3) ? Wob : (Wqkvb + (size_t)seg * 1048576);
    }
    float4 v = reinterpret_cast<const float4*>(src)[idx];
    ushort4 o;
    o.x = f2b(v.x); o.y = f2b(v.y); o.z = f2b(v.z); o.w = f2b(v.w);
    reinterpret_cast<ushort4*>(dst)[idx] = o;
    return;
  }
  // ---- top-3 (softmax monotonic -> top-k of raw scores), one block ----
  __shared__ float svals[256];
  __shared__ int   sidx[256];
  __shared__ int   chosen[3];
  const int t = threadIdx.x;
  for (int pass = 0; pass < 3; ++pass) {
    float best = -INFINITY; int bi = 1 << 30;
    for (int j = t; j < 2048; j += 256) {
      float v = band[j];
      bool skip = false;
      for (int p2 = 0; p2 < pass; ++p2) skip |= (chosen[p2] == j);
      if (!skip && (v > best || (v == best && j < bi))) { best = v; bi = j; }
    }
    svals[t] = best; sidx[t] = bi;
    __syncthreads();
    for (int s = 128; s > 0; s >>= 1) {
      if (t < s) {
        float v2 = svals[t + s]; int i2 = sidx[t + s];
        if (v2 > svals[t] || (v2 == svals[t] && i2 < sidx[t])) { svals[t] = v2; sidx[t] = i2; }
      }
      __syncthreads();
    }
    if (t == 0) chosen[pass] = sidx[0];
    __syncthreads();
  }
  if (t < 3) idxout[t] = chosen[t];
}

// ---------- fused QKV GEMM, 256x256 tile, BK=32, 8 waves, tri-buffered pipeline ----------
__global__ __launch_bounds__(512, 1) void gemm_qkv256(
    const unsigned short* __restrict__ A,
    const unsigned short* __restrict__ Wqkv,
    const float* __restrict__ bq, const float* __restrict__ bk,
    const float* __restrict__ bv,
    unsigned short* __restrict__ qout, unsigned short* __restrict__ kout,
    unsigned short* __restrict__ vtout, float qscale)
{
  __shared__ short Ls[3][2][8192];       // [buf][A=0/B=1][256 rows x 32 cols]
  const int tid = threadIdx.x;
  const int w = tid >> 6, lane = tid & 63;
  const int wm = w >> 2, wn = w & 3;     // 2 x 4 wave grid; wave out = 128 x 64
  const int flat = blockIdx.y * 32 + blockIdx.x;   // 384 blocks, %8==0
  const int swb = (flat & 7) * 48 + (flat >> 3);
  const int m0 = (swb & 31) * 256, n0 = (swb >> 5) * 256;

  const int seg = n0 >> 10;              // block entirely within one of Q/K/V
  const float* biasp = (seg == 0) ? bq : (seg == 1) ? bk : bv;
  const float scale = (seg == 0) ? qscale : 1.0f;

  f32x4 acc[8][4];
  #pragma unroll
  for (int mt = 0; mt < 8; ++mt)
    #pragma unroll
    for (int nt = 0; nt < 4; ++nt)
      #pragma unroll
      for (int r = 0; r < 4; ++r) acc[mt][nt][r] = 0.f;

  const int srow = tid >> 2;                                   // 0..127
  const int scol = ((tid & 3) ^ ((srow >> 2) & 3)) * 8;        // pre-swizzled src col
  const unsigned short* ap = A + (size_t)(m0 + srow) * 1024 + scol;
  const unsigned short* bp = Wqkv + (size_t)(n0 + srow) * 1024 + scol;
  const int ldst = tid * 8;                                    // linear LDS dest (shorts)

#define STG_A0(bufi, tt) __builtin_amdgcn_global_load_lds(                     \
    (const GAS void*)(ap + (size_t)(tt) * 32), (LAS void*)&Ls[bufi][0][ldst], 16, 0, 0)
#define STG_A1(bufi, tt) __builtin_amdgcn_global_load_lds(                     \
    (const GAS void*)(ap + (size_t)(tt) * 32 + 131072), (LAS void*)&Ls[bufi][0][4096 + ldst], 16, 0, 0)
#define STG_B0(bufi, tt) __builtin_amdgcn_global_load_lds(                     \
    (const GAS void*)(bp + (size_t)(tt) * 32), (LAS void*)&Ls[bufi][1][ldst], 16, 0, 0)
#define STG_B1(bufi, tt) __builtin_amdgcn_global_load_lds(                     \
    (const GAS void*)(bp + (size_t)(tt) * 32 + 131072), (LAS void*)&Ls[bufi][1][4096 + ldst], 16, 0, 0)

  const int r15 = lane & 15;
  const int fcol = ((lane >> 4) * 8) ^ (((r15 >> 2) & 3) << 3);
  const int arow0 = wm * 128 + r15;      // + mt*16
  const int brow0 = wn * 64 + r15;       // + nt*16

  STG_A0(0, 0); STG_A1(0, 0); STG_B0(0, 0); STG_B1(0, 0);
  STG_A0(1, 1); STG_A1(1, 1); STG_B0(1, 1); STG_B1(1, 1);

  for (int t = 0; t < 32; ++t) {
    if (t < 31) { asm volatile("s_waitcnt vmcnt(4)" ::: "memory"); }
    else        { asm volatile("s_waitcnt vmcnt(0)" ::: "memory"); }
    __builtin_amdgcn_sched_barrier(0);
    __builtin_amdgcn_s_barrier();        // tile-t resident; prev-tile reads drained
    __builtin_amdgcn_sched_barrier(0);
    const int buf = t % 3;
    const int sbuf = (t + 2) % 3;        // last read in tile t-1 -> safe to fill now
    const short* Ab = &Ls[buf][0][0];
    const short* Bb = &Ls[buf][1][0];

    short8 bf[4];
    #pragma unroll
    for (int nt = 0; nt < 4; ++nt)
      bf[nt] = *reinterpret_cast<const short8*>(&Bb[(brow0 + nt * 16) * 32 + fcol]);

    #pragma unroll
    for (int ph = 0; ph < 4; ++ph) {
      if (t < 30) {
        if (ph == 0) STG_A0(sbuf, t + 2);
        else if (ph == 1) STG_A1(sbuf, t + 2);
        else if (ph == 2) STG_B0(sbuf, t + 2);
        else STG_B1(sbuf, t + 2);
      }
      short8 a0 = *reinterpret_cast<const short8*>(&Ab[(arow0 + (ph * 2) * 16) * 32 + fcol]);
      short8 a1 = *reinterpret_cast<const short8*>(&Ab[(arow0 + (ph * 2 + 1) * 16) * 32 + fcol]);
      __builtin_amdgcn_s_setprio(1);
      #pragma unroll
      for (int nt = 0; nt < 4; ++nt) {
        acc[ph * 2][nt] = MFMA16(a0, bf[nt], acc[ph * 2][nt]);
        acc[ph * 2 + 1][nt] = MFMA16(a1, bf[nt], acc[ph * 2 + 1][nt]);
      }
      __builtin_amdgcn_s_setprio(0);
    }

    asm volatile("s_waitcnt lgkmcnt(0)" ::: "memory");  // my reads of buf done
    __builtin_amdgcn_sched_barrier(0);
  }

  if (seg == 2) {
    #pragma unroll
    for (int nt = 0; nt < 4; ++nt) {
      int coll = (n0 + wn * 64 + nt * 16 + r15) & 1023;
      float bval = biasp[coll];
      int h_ = coll >> 6, d_ = coll & 63;
      #pragma unroll
      for (int mt = 0; mt < 8; ++mt) {
        int rbase = m0 + wm * 128 + mt * 16 + ((lane >> 4) << 2);
        int b_ = rbase >> 11, lt_ = rbase & 2047;   // quad never crosses batch
        ushort4 pk;
        pk.x = f2b(acc[mt][nt][0] + bval);
        pk.y = f2b(acc[mt][nt][1] + bval);
        pk.z = f2b(acc[mt][nt][2] + bval);
        pk.w = f2b(acc[mt][nt][3] + bval);
        *reinterpret_cast<ushort4*>(
            &vtout[(((size_t)(b_ * 16 + h_)) * 64 + d_) * 2048 + lt_]) = pk;
      }
    }
  } else {
    unsigned short* outp = (seg == 0) ? qout : kout;
    #pragma unroll
    for (int nt = 0; nt < 4; ++nt) {
      int coll = (n0 + wn * 64 + nt * 16 + r15) & 1023;
      float bval = biasp[coll];
      int h_ = coll >> 6, d_ = coll & 63;
      #pragma unroll
      for (int mt = 0; mt < 8; ++mt) {
        int rbase = m0 + wm * 128 + mt * 16 + ((lane >> 4) << 2);
        #pragma unroll
        for (int r = 0; r < 4; ++r) {
          unsigned short val = f2b((acc[mt][nt][r] + bval) * scale);
          int row = rbase + r;
          int b_ = row >> 11, lt_ = row & 2047;
          outp[(((size_t)(b_ * 16 + h_)) * 2048 + lt_) * 64 + d_] = val;
        }
      }
    }
  }
}

// ---------- Wo GEMM: token-major C = A * Wo^T + bo (128^2, known-good) ----------
__global__ __launch_bounds__(256) void gemm_wo(
    const unsigned short* __restrict__ A,   // [8192][1024]
    const unsigned short* __restrict__ Bw,  // [1024][1024]
    const float* __restrict__ bias,
    unsigned short* __restrict__ C)
{
  __shared__ short As[128][64];
  __shared__ short Bs[128][64];
  const int tid = threadIdx.x;
  const int w = tid >> 6, lane = tid & 63;
  const int wm = w >> 1, wn = w & 1;
  const int flat = blockIdx.y * 64 + blockIdx.x;   // total 512
  const int swb = (flat & 7) * 64 + (flat >> 3);
  const int m0 = (swb & 63) * 128, n0 = (swb >> 6) * 128;
  const int rA = lane >> 3, cA = lane & 7;

  f32x4 acc[4][4];
  #pragma unroll
  for (int mt = 0; mt < 4; ++mt)
    #pragma unroll
    for (int nt = 0; nt < 4; ++nt)
      #pragma unroll
      for (int r = 0; r < 4; ++r) acc[mt][nt][r] = 0.f;

  for (int kt = 0; kt < 16; ++kt) {
    #pragma unroll
    for (int j = 0; j < 4; ++j) {
      int r = w * 32 + j * 8;
      const unsigned short* ga = A + (size_t)(m0 + r + rA) * 1024 + kt * 64 + cA * 8;
      __builtin_amdgcn_global_load_lds((const GAS void*)ga, (LAS void*)&As[r][0], 16, 0, 0);
      const unsigned short* gb = Bw + (size_t)(n0 + r + rA) * 1024 + kt * 64 + cA * 8;
      __builtin_amdgcn_global_load_lds((const GAS void*)gb, (LAS void*)&Bs[r][0], 16, 0, 0);
    }
    __syncthreads();
    #pragma unroll
    for (int kc = 0; kc < 2; ++kc) {
      short8 a[4], b[4];
      #pragma unroll
      for (int mt = 0; mt < 4; ++mt)
        a[mt] = *reinterpret_cast<const short8*>(
            &As[wm * 64 + mt * 16 + (lane & 15)][kc * 32 + (lane >> 4) * 8]);
      #pragma unroll
      for (int nt = 0; nt < 4; ++nt)
        b[nt] = *reinterpret_cast<const short8*>(
            &Bs[wn * 64 + nt * 16 + (lane & 15)][kc * 32 + (lane >> 4) * 8]);
      __builtin_amdgcn_s_setprio(1);
      #pragma unroll
      for (int mt = 0; mt < 4; ++mt)
        #pragma unroll
        for (int nt = 0; nt < 4; ++nt)
          acc[mt][nt] = MFMA16(a[mt], b[nt], acc[mt][nt]);
      __builtin_amdgcn_s_setprio(0);
    }
    __syncthreads();
  }
  #pragma unroll
  for (int nt = 0; nt < 4; ++nt) {
    int col = n0 + wn * 64 + nt * 16 + (lane & 15);
    float bval = bias[col];
    #pragma unroll
    for (int mt = 0; mt < 4; ++mt) {
      int rbase = m0 + wm * 64 + mt * 16 + ((lane >> 4) << 2);
      #pragma unroll
      for (int r = 0; r < 4; ++r)
        C[(size_t)(rbase + r) * 1024 + col] = f2b(acc[mt][nt][r] + bval);
    }
  }
}

// ---------- flash attention: 8 waves x 32q (Q-tile 256), static-max, 2 barriers/tile ----------
#define PACK8(S, j0, OUT) {                                        \
    unsigned A_ = cvtpk(S[(j0)+0], S[(j0)+1]);                     \
    unsigned B_ = cvtpk(S[(j0)+4], S[(j0)+5]);                     \
    unsigned C_ = cvtpk(S[(j0)+2], S[(j0)+3]);                     \
    unsigned D_ = cvtpk(S[(j0)+6], S[(j0)+7]);                     \
    pl32swap(A_, B_); pl32swap(C_, D_);                            \
    FW f_; f_.u[0] = A_; f_.u[1] = C_; f_.u[2] = B_; f_.u[3] = D_; \
    OUT = f_.s; }

__global__ __launch_bounds__(512, 4) void attn8(
    const unsigned short* __restrict__ qg,
    const unsigned short* __restrict__ kg,
    const unsigned short* __restrict__ vtg,
    const int* __restrict__ midx,
    unsigned short* __restrict__ ctx)
{
  __shared__ short Ks[2][64 * 64];
  __shared__ short Vs[2][64 * 64];
  const int tid = threadIdx.x, w = tid >> 6, lane = tid & 63;
  // XCD swizzle: 512 blocks; 64 consecutive swzb per XCD -> 8 bh per XCD
  const int flat = blockIdx.y * 8 + blockIdx.x;
  const int swzb = (flat & 7) * 64 + (flat >> 3);
  const int qt = swzb & 7, bh = swzb >> 3;
  const int q0 = qt * 256;
  const int lo5 = lane & 31, hi = lane >> 5;
  const int i0 = midx[0], i1 = midx[1], i2 = midx[2];

  // Q fragments (B-operand), pre-scaled by 0.125*log2e; wave owns q-rows [w*32, w*32+32)
  const int qrow = q0 + w * 32 + lo5;
  const unsigned short* qp = qg + ((size_t)bh * 2048 + qrow) * 64 + hi * 8;
  short8 qf[4];
  #pragma unroll
  for (int ds = 0; ds < 4; ++ds) qf[ds] = ld8(qp + ds * 16);

  f32x16 oacc0, oacc1, lacc;
  #pragma unroll
  for (int r = 0; r < 16; ++r) { oacc0[r] = 0.f; oacc1[r] = 0.f; lacc[r] = 0.f; }

  // staging: thread tid covers row tid>>3, col chunk tid&7 (pre-swizzled source)
  const int srow = tid >> 3;
  const int swzoff = (((tid & 7) ^ (srow & 7))) * 8;
  const unsigned short* kp = kg + ((size_t)bh * 2048 + srow) * 64 + swzoff;
  const unsigned short* vp = vtg + ((size_t)bh * 64 + srow) * 2048 + swzoff;

#define STAGE8(bufi, tt) do {                                                  \
    __builtin_amdgcn_global_load_lds((const GAS void*)(kp + (size_t)(tt) * 4096), \
        (LAS void*)&Ks[bufi][w * 512], 16, 0, 0);                              \
    __builtin_amdgcn_global_load_lds((const GAS void*)(vp + (tt) * 64),        \
        (LAS void*)&Vs[bufi][w * 512], 16, 0, 0);                              \
  } while (0)

  // depth-2 prologue: tiles 0,1 staged (4 loads/wave outstanding)
  STAGE8(0, 0);
  STAGE8(1, 1);

  for (int t = 0; t < 32; ++t) {
    const int buf = t & 1;
    // entry: tile t's K+V (2 oldest) drained; tile t+1's 2 stay in flight
    if (t < 31) { asm volatile("s_waitcnt vmcnt(2)" ::: "memory"); }
    else        { asm volatile("s_waitcnt vmcnt(0)" ::: "memory"); }
    __builtin_amdgcn_sched_barrier(0);
    __builtin_amdgcn_s_barrier();          // all waves' tile-t data resident
    __builtin_amdgcn_sched_barrier(0);

    // ---- K fragments -> regs ----
    short8 kf[8];
    #pragma unroll
    for (int ds = 0; ds < 4; ++ds) {
      int cw = ds * 2 + hi;
      kf[2 * ds] = *reinterpret_cast<const short8*>(
          &Ks[buf][lo5 * 64 + ((cw ^ (lo5 & 7)) * 8)]);
      kf[2 * ds + 1] = *reinterpret_cast<const short8*>(
          &Ks[buf][(32 + lo5) * 64 + ((cw ^ (lo5 & 7)) * 8)]);
    }

    // ---- S^T = K . Q^T ----
    f32x16 s0, s1;
    #pragma unroll
    for (int r = 0; r < 16; ++r) { s0[r] = 0.f; s1[r] = 0.f; }
    __builtin_amdgcn_s_setprio(1);
    #pragma unroll
    for (int ds = 0; ds < 4; ++ds) {
      s0 = MFMA32(kf[2 * ds], qf[ds], s0);
      s1 = MFMA32(kf[2 * ds + 1], qf[ds], s1);
    }
    __builtin_amdgcn_s_setprio(0);

    // ---- V fragments -> regs (latency hidden under softmax) ----
    short8 vf[8];
    #pragma unroll
    for (int ks = 0; ks < 4; ++ks) {
      int cw = ks * 2 + hi;
      vf[2 * ks] = *reinterpret_cast<const short8*>(
          &Vs[buf][lo5 * 64 + ((cw ^ (lo5 & 7)) * 8)]);
      vf[2 * ks + 1] = *reinterpret_cast<const short8*>(
          &Vs[buf][(32 + lo5) * 64 + ((cw ^ (lo5 & 7)) * 8)]);
    }

    // ---- static-max softmax: p = 2^s (scale folded into Q) ----
    #pragma unroll
    for (int r = 0; r < 16; ++r) s0[r] = fexp2(s0[r]);
    #pragma unroll
    for (int r = 0; r < 16; ++r) s1[r] = fexp2(s1[r]);

    int t64 = t * 64;
    bool tm = ((unsigned)(i0 - t64) < 64u) | ((unsigned)(i1 - t64) < 64u) |
              ((unsigned)(i2 - t64) < 64u);
    if (tm) {
      #pragma unroll
      for (int r = 0; r < 16; ++r) {
        int kg0 = t64 + (r & 3) + 8 * (r >> 2) + 4 * hi;
        int kg1 = kg0 + 32;
        if (kg0 == i0 || kg0 == i1 || kg0 == i2) s0[r] = 0.f;
        if (kg1 == i0 || kg1 == i1 || kg1 == i2) s1[r] = 0.f;
      }
    }

    #pragma unroll
    for (int r = 0; r < 16; ++r) lacc[r] += s0[r] + s1[r];

    short8 pa[4];
    PACK8(s0, 0, pa[0]); PACK8(s0, 8, pa[1]);
    PACK8(s1, 0, pa[2]); PACK8(s1, 8, pa[3]);

    // ---- release barrier: all waves done reading Ks/Vs[buf] ----
    asm volatile("s_waitcnt lgkmcnt(0)" ::: "memory");
    __builtin_amdgcn_sched_barrier(0);
    __builtin_amdgcn_s_barrier();
    __builtin_amdgcn_sched_barrier(0);
    if (t < 30) STAGE8(buf, t + 2);        // refill buf with tile t+2

    // ---- O += P . V ----
    __builtin_amdgcn_s_setprio(1);
    #pragma unroll
    for (int ks = 0; ks < 4; ++ks) {
      oacc0 = MFMA32(pa[ks], vf[2 * ks], oacc0);
      oacc1 = MFMA32(pa[ks], vf[2 * ks + 1], oacc1);
    }
    __builtin_amdgcn_s_setprio(0);
  }

  // ---- epilogue: ctx = O / lsum, token-major ----
  float lsum = 0.f;
  #pragma unroll
  for (int r = 0; r < 16; ++r) lsum += lacc[r];
  lsum = xhalf_sum(lsum);
  const int bb = bh >> 4, hh = bh & 15;
  float rinv = 1.0f / lsum;
  #pragma unroll
  for (int r = 0; r < 16; ++r) {
    int row = (r & 3) + 8 * (r >> 2) + 4 * hi;
    float rv = __int_as_float(__builtin_amdgcn_ds_bpermute(
        (row + (lane & 32)) * 4, __float_as_int(rinv)));
    int qr = q0 + w * 32 + row;
    size_t base = (((size_t)(bb * 2048 + qr)) * 16 + hh) * 64;
    ctx[base + lo5]      = f2b(oacc0[r] * rv);
    ctx[base + 32 + lo5] = f2b(oacc1[r] * rv);
  }
}

// ---------- residual + LayerNorm ----------
__global__ __launch_bounds__(256) void resid_ln(
    const float* __restrict__ x, const unsigned short* __restrict__ ao,
    const float* __restrict__ gamma, const float* __restrict__ beta,
    float* __restrict__ out)
{
  const int row = blockIdx.x, t = threadIdx.x;
  const size_t base = (size_t)row * 1024;
  float4 xv = reinterpret_cast<const float4*>(x + base)[t];
  ushort4 av = reinterpret_cast<const ushort4*>(ao + base)[t];
  float y[4] = {xv.x + b2f(av.x), xv.y + b2f(av.y), xv.z + b2f(av.z), xv.w + b2f(av.w)};
  float sum = y[0] + y[1] + y[2] + y[3];
  float sq = y[0] * y[0] + y[1] * y[1] + y[2] * y[2] + y[3] * y[3];
  #pragma unroll
  for (int off = 1; off < 64; off <<= 1) {
    sum += __shfl_xor(sum, off);
    sq += __shfl_xor(sq, off);
  }
  __shared__ float s1[4], s2[4];
  int w = t >> 6, lane = t & 63;
  if (lane == 0) { s1[w] = sum; s2[w] = sq; }
  __syncthreads();
  sum = s1[0] + s1[1] + s1[2] + s1[3];
  sq = s2[0] + s2[1] + s2[2] + s2[3];
  float mu = sum * (1.f / 1024.f);
  float var = sq * (1.f / 1024.f) - mu * mu;
  float inv = rsqrtf(var + 1e-5f);
  float4 gv = reinterpret_cast<const float4*>(gamma)[t];
  float4 bv = reinterpret_cast<const float4*>(beta)[t];
  float4 o;
  o.x = (y[0] - mu) * inv * gv.x + bv.x;
  o.y = (y[1] - mu) * inv * gv.y + bv.y;
  o.z = (y[2] - mu) * inv * gv.z + bv.z;
  o.w = (y[3] - mu) * inv * gv.w + bv.w;
  reinterpret_cast<float4*>(out + base)[t] = o;
}

// ---------- launch ----------
extern "C" void kernel_launch(void* const* d_in, const int* in_sizes, int n_in,
                              void* d_out, int out_size, void* d_ws, size_t ws_size,
                              hipStream_t stream)
{
  const float* x     = (const float*)d_in[0];
  const float* band  = (const float*)d_in[1];
  const float* Wq    = (const float*)d_in[2];
  const float* bq    = (const float*)d_in[3];
  const float* Wk    = (const float*)d_in[4];
  const float* bk    = (const float*)d_in[5];
  const float* Wv    = (const float*)d_in[6];
  const float* bv    = (const float*)d_in[7];
  const float* Wo    = (const float*)d_in[8];
  const float* bo    = (const float*)d_in[9];
  const float* gamma = (const float*)d_in[10];
  const float* beta  = (const float*)d_in[11];
  float* out = (float*)d_out;

  char* ws = (char*)d_ws;
  int*            idxw  = (int*)(ws);                          // 16 B
  unsigned short* xb    = (unsigned short*)(ws + 4096);        // 16 MB
  unsigned short* Wqkvb = (unsigned short*)(ws + 16781312);    // 6 MB [3072][1024]
  unsigned short* Wob   = (unsigned short*)(ws + 23072768);    // 2 MB
  unsigned short* qb    = (unsigned short*)(ws + 25169920);    // head-major, pre-scaled
  unsigned short* kb    = (unsigned short*)(ws + 41947136);    // head-major
  unsigned short* ctxb  = (unsigned short*)(ws + 58724352);    // token-major ctx
  unsigned short* vtb   = (unsigned short*)(ws + 75501568);    // V^T [BH][64][L]
  unsigned short* aob   = qb;                                  // reuse after attn

  const float QSCALE = 0.125f * 1.44269504f;  // softmax scale + log2(e) folded into Q

  cvt_topk<<<12289, 256, 0, stream>>>(x, Wq, Wk, Wv, Wo, band, xb, Wqkvb, Wob, idxw);

  gemm_qkv256<<<dim3(32, 12), 512, 0, stream>>>(xb, Wqkvb, bq, bk, bv,
                                                qb, kb, vtb, QSCALE);

  attn8<<<dim3(8, 64), 512, 0, stream>>>(qb, kb, vtb, idxw, ctxb);

  gemm_wo<<<dim3(64, 8), 256, 0, stream>>>(ctxb, Wob, bo, aob);

  resid_ln<<<8192, 256, 0, stream>>>(x, aob, gamma, beta, out);
}

// Round 10
// 225.931 us; speedup vs baseline: 1.6336x; 1.6336x over previous
//
#include <hip/hip_runtime.h>

#define GAS __attribute__((address_space(1)))
#define LAS __attribute__((address_space(3)))

typedef __attribute__((ext_vector_type(8))) short short8;
typedef __attribute__((ext_vector_type(4))) float f32x4;
typedef __attribute__((ext_vector_type(16))) float f32x16;
typedef __attribute__((ext_vector_type(4))) unsigned int u32x4;

#define MFMA16(a,b,c) __builtin_amdgcn_mfma_f32_16x16x32_bf16(a,b,c,0,0,0)
#define MFMA32(a,b,c) __builtin_amdgcn_mfma_f32_32x32x16_bf16(a,b,c,0,0,0)

// ---------- bf16 helpers ----------
__device__ __forceinline__ unsigned short f2b(float f) {
  unsigned u = __float_as_uint(f);
  u += 0x7fffu + ((u >> 16) & 1u);          // RNE
  return (unsigned short)(u >> 16);
}
__device__ __forceinline__ float b2f(unsigned short h) {
  return __uint_as_float(((unsigned)h) << 16);
}
__device__ __forceinline__ unsigned cvtpk(float a, float b) {
  unsigned r;
  asm("v_cvt_pk_bf16_f32 %0, %1, %2" : "=v"(r) : "v"(a), "v"(b));
  return r;
}
__device__ __forceinline__ void pl32swap(unsigned &x, unsigned &y) {
  auto r = __builtin_amdgcn_permlane32_swap((int)x, (int)y, false, false);
  x = (unsigned)r[0]; y = (unsigned)r[1];
}
__device__ __forceinline__ float xhalf_sum(float v) {
  auto r = __builtin_amdgcn_permlane32_swap(__float_as_int(v), __float_as_int(v), false, false);
  return __int_as_float(r[0]) + __int_as_float(r[1]);
}
__device__ __forceinline__ float fexp2(float x) {
  float r;
  asm("v_exp_f32 %0, %1" : "=v"(r) : "v"(x));   // D = 2^S0
  return r;
}
__device__ __forceinline__ short8 ld8(const unsigned short* p) {
  return *reinterpret_cast<const short8*>(p);
}

union FW { u32x4 u; short8 s; };

// ---------- fused fp32 -> bf16 convert (x + weights) + top-3 mask indices ----------
__global__ void cvt_topk(const float* __restrict__ x,
                         const float* __restrict__ Wq, const float* __restrict__ Wk,
                         const float* __restrict__ Wv, const float* __restrict__ Wo,
                         const float* __restrict__ band,
                         unsigned short* __restrict__ xb,
                         unsigned short* __restrict__ Wqkvb,
                         unsigned short* __restrict__ Wob,
                         int* __restrict__ idxout) {
  const int bid = blockIdx.x;
  if (bid < 12288) {
    const float* src;
    unsigned short* dst;
    int idx;
    if (bid < 8192) {                     // x: 2097152 float4
      src = x; dst = xb; idx = bid * 256 + threadIdx.x;
    } else {                              // weights: 4 x 262144 float4
      int wb = bid - 8192;
      int seg = wb >> 10;
      idx = (wb & 1023) * 256 + threadIdx.x;
      src = (seg == 0) ? Wq : (seg == 1) ? Wk : (seg == 2) ? Wv : Wo;
      dst = (seg == 3) ? Wob : (Wqkvb + (size_t)seg * 1048576);
    }
    float4 v = reinterpret_cast<const float4*>(src)[idx];
    ushort4 o;
    o.x = f2b(v.x); o.y = f2b(v.y); o.z = f2b(v.z); o.w = f2b(v.w);
    reinterpret_cast<ushort4*>(dst)[idx] = o;
    return;
  }
  // ---- top-3 (softmax monotonic -> top-k of raw scores), one block ----
  __shared__ float svals[256];
  __shared__ int   sidx[256];
  __shared__ int   chosen[3];
  const int t = threadIdx.x;
  for (int pass = 0; pass < 3; ++pass) {
    float best = -INFINITY; int bi = 1 << 30;
    for (int j = t; j < 2048; j += 256) {
      float v = band[j];
      bool skip = false;
      for (int p2 = 0; p2 < pass; ++p2) skip |= (chosen[p2] == j);
      if (!skip && (v > best || (v == best && j < bi))) { best = v; bi = j; }
    }
    svals[t] = best; sidx[t] = bi;
    __syncthreads();
    for (int s = 128; s > 0; s >>= 1) {
      if (t < s) {
        float v2 = svals[t + s]; int i2 = sidx[t + s];
        if (v2 > svals[t] || (v2 == svals[t] && i2 < sidx[t])) { svals[t] = v2; sidx[t] = i2; }
      }
      __syncthreads();
    }
    if (t == 0) chosen[pass] = sidx[0];
    __syncthreads();
  }
  if (t < 3) idxout[t] = chosen[t];
}

// ---------- fused QKV GEMM, 256x256 tile, BK=32, 8 waves, tri-buffered pipeline ----------
__global__ __launch_bounds__(512, 1) void gemm_qkv256(
    const unsigned short* __restrict__ A,
    const unsigned short* __restrict__ Wqkv,
    const float* __restrict__ bq, const float* __restrict__ bk,
    const float* __restrict__ bv,
    unsigned short* __restrict__ qout, unsigned short* __restrict__ kout,
    unsigned short* __restrict__ vtout, float qscale)
{
  __shared__ short Ls[3][2][8192];       // [buf][A=0/B=1][256 rows x 32 cols]
  const int tid = threadIdx.x;
  const int w = tid >> 6, lane = tid & 63;
  const int wm = w >> 2, wn = w & 3;     // 2 x 4 wave grid; wave out = 128 x 64
  const int flat = blockIdx.y * 32 + blockIdx.x;   // 384 blocks, %8==0
  const int swb = (flat & 7) * 48 + (flat >> 3);
  const int m0 = (swb & 31) * 256, n0 = (swb >> 5) * 256;

  const int seg = n0 >> 10;              // block entirely within one of Q/K/V
  const float* biasp = (seg == 0) ? bq : (seg == 1) ? bk : bv;
  const float scale = (seg == 0) ? qscale : 1.0f;

  f32x4 acc[8][4];
  #pragma unroll
  for (int mt = 0; mt < 8; ++mt)
    #pragma unroll
    for (int nt = 0; nt < 4; ++nt)
      #pragma unroll
      for (int r = 0; r < 4; ++r) acc[mt][nt][r] = 0.f;

  const int srow = tid >> 2;                                   // 0..127
  const int scol = ((tid & 3) ^ ((srow >> 2) & 3)) * 8;        // pre-swizzled src col
  const unsigned short* ap = A + (size_t)(m0 + srow) * 1024 + scol;
  const unsigned short* bp = Wqkv + (size_t)(n0 + srow) * 1024 + scol;
  const int ldst = tid * 8;                                    // linear LDS dest (shorts)

#define STG_A0(bufi, tt) __builtin_amdgcn_global_load_lds(                     \
    (const GAS void*)(ap + (size_t)(tt) * 32), (LAS void*)&Ls[bufi][0][ldst], 16, 0, 0)
#define STG_A1(bufi, tt) __builtin_amdgcn_global_load_lds(                     \
    (const GAS void*)(ap + (size_t)(tt) * 32 + 131072), (LAS void*)&Ls[bufi][0][4096 + ldst], 16, 0, 0)
#define STG_B0(bufi, tt) __builtin_amdgcn_global_load_lds(                     \
    (const GAS void*)(bp + (size_t)(tt) * 32), (LAS void*)&Ls[bufi][1][ldst], 16, 0, 0)
#define STG_B1(bufi, tt) __builtin_amdgcn_global_load_lds(                     \
    (const GAS void*)(bp + (size_t)(tt) * 32 + 131072), (LAS void*)&Ls[bufi][1][4096 + ldst], 16, 0, 0)

  const int r15 = lane & 15;
  const int fcol = ((lane >> 4) * 8) ^ (((r15 >> 2) & 3) << 3);
  const int arow0 = wm * 128 + r15;      // + mt*16
  const int brow0 = wn * 64 + r15;       // + nt*16

  STG_A0(0, 0); STG_A1(0, 0); STG_B0(0, 0); STG_B1(0, 0);
  STG_A0(1, 1); STG_A1(1, 1); STG_B0(1, 1); STG_B1(1, 1);

  for (int t = 0; t < 32; ++t) {
    if (t < 31) { asm volatile("s_waitcnt vmcnt(4)" ::: "memory"); }
    else        { asm volatile("s_waitcnt vmcnt(0)" ::: "memory"); }
    __builtin_amdgcn_sched_barrier(0);
    __builtin_amdgcn_s_barrier();        // tile-t resident; prev-tile reads drained
    __builtin_amdgcn_sched_barrier(0);
    const int buf = t % 3;
    const int sbuf = (t + 2) % 3;        // last read in tile t-1 -> safe to fill now
    const short* Ab = &Ls[buf][0][0];
    const short* Bb = &Ls[buf][1][0];

    short8 bf[4];
    #pragma unroll
    for (int nt = 0; nt < 4; ++nt)
      bf[nt] = *reinterpret_cast<const short8*>(&Bb[(brow0 + nt * 16) * 32 + fcol]);

    #pragma unroll
    for (int ph = 0; ph < 4; ++ph) {
      if (t < 30) {
        if (ph == 0) STG_A0(sbuf, t + 2);
        else if (ph == 1) STG_A1(sbuf, t + 2);
        else if (ph == 2) STG_B0(sbuf, t + 2);
        else STG_B1(sbuf, t + 2);
      }
      short8 a0 = *reinterpret_cast<const short8*>(&Ab[(arow0 + (ph * 2) * 16) * 32 + fcol]);
      short8 a1 = *reinterpret_cast<const short8*>(&Ab[(arow0 + (ph * 2 + 1) * 16) * 32 + fcol]);
      __builtin_amdgcn_s_setprio(1);
      #pragma unroll
      for (int nt = 0; nt < 4; ++nt) {
        acc[ph * 2][nt] = MFMA16(a0, bf[nt], acc[ph * 2][nt]);
        acc[ph * 2 + 1][nt] = MFMA16(a1, bf[nt], acc[ph * 2 + 1][nt]);
      }
      __builtin_amdgcn_s_setprio(0);
    }

    asm volatile("s_waitcnt lgkmcnt(0)" ::: "memory");  // my reads of buf done
    __builtin_amdgcn_sched_barrier(0);
  }

  if (seg == 2) {
    #pragma unroll
    for (int nt = 0; nt < 4; ++nt) {
      int coll = (n0 + wn * 64 + nt * 16 + r15) & 1023;
      float bval = biasp[coll];
      int h_ = coll >> 6, d_ = coll & 63;
      #pragma unroll
      for (int mt = 0; mt < 8; ++mt) {
        int rbase = m0 + wm * 128 + mt * 16 + ((lane >> 4) << 2);
        int b_ = rbase >> 11, lt_ = rbase & 2047;   // quad never crosses batch
        ushort4 pk;
        pk.x = f2b(acc[mt][nt][0] + bval);
        pk.y = f2b(acc[mt][nt][1] + bval);
        pk.z = f2b(acc[mt][nt][2] + bval);
        pk.w = f2b(acc[mt][nt][3] + bval);
        *reinterpret_cast<ushort4*>(
            &vtout[(((size_t)(b_ * 16 + h_)) * 64 + d_) * 2048 + lt_]) = pk;
      }
    }
  } else {
    unsigned short* outp = (seg == 0) ? qout : kout;
    #pragma unroll
    for (int nt = 0; nt < 4; ++nt) {
      int coll = (n0 + wn * 64 + nt * 16 + r15) & 1023;
      float bval = biasp[coll];
      int h_ = coll >> 6, d_ = coll & 63;
      #pragma unroll
      for (int mt = 0; mt < 8; ++mt) {
        int rbase = m0 + wm * 128 + mt * 16 + ((lane >> 4) << 2);
        #pragma unroll
        for (int r = 0; r < 4; ++r) {
          unsigned short val = f2b((acc[mt][nt][r] + bval) * scale);
          int row = rbase + r;
          int b_ = row >> 11, lt_ = row & 2047;
          outp[(((size_t)(b_ * 16 + h_)) * 2048 + lt_) * 64 + d_] = val;
        }
      }
    }
  }
}

// ---------- Wo GEMM: token-major C = A * Wo^T + bo (128^2, known-good) ----------
__global__ __launch_bounds__(256) void gemm_wo(
    const unsigned short* __restrict__ A,   // [8192][1024]
    const unsigned short* __restrict__ Bw,  // [1024][1024]
    const float* __restrict__ bias,
    unsigned short* __restrict__ C)
{
  __shared__ short As[128][64];
  __shared__ short Bs[128][64];
  const int tid = threadIdx.x;
  const int w = tid >> 6, lane = tid & 63;
  const int wm = w >> 1, wn = w & 1;
  const int flat = blockIdx.y * 64 + blockIdx.x;   // total 512
  const int swb = (flat & 7) * 64 + (flat >> 3);
  const int m0 = (swb & 63) * 128, n0 = (swb >> 6) * 128;
  const int rA = lane >> 3, cA = lane & 7;

  f32x4 acc[4][4];
  #pragma unroll
  for (int mt = 0; mt < 4; ++mt)
    #pragma unroll
    for (int nt = 0; nt < 4; ++nt)
      #pragma unroll
      for (int r = 0; r < 4; ++r) acc[mt][nt][r] = 0.f;

  for (int kt = 0; kt < 16; ++kt) {
    #pragma unroll
    for (int j = 0; j < 4; ++j) {
      int r = w * 32 + j * 8;
      const unsigned short* ga = A + (size_t)(m0 + r + rA) * 1024 + kt * 64 + cA * 8;
      __builtin_amdgcn_global_load_lds((const GAS void*)ga, (LAS void*)&As[r][0], 16, 0, 0);
      const unsigned short* gb = Bw + (size_t)(n0 + r + rA) * 1024 + kt * 64 + cA * 8;
      __builtin_amdgcn_global_load_lds((const GAS void*)gb, (LAS void*)&Bs[r][0], 16, 0, 0);
    }
    __syncthreads();
    #pragma unroll
    for (int kc = 0; kc < 2; ++kc) {
      short8 a[4], b[4];
      #pragma unroll
      for (int mt = 0; mt < 4; ++mt)
        a[mt] = *reinterpret_cast<const short8*>(
            &As[wm * 64 + mt * 16 + (lane & 15)][kc * 32 + (lane >> 4) * 8]);
      #pragma unroll
      for (int nt = 0; nt < 4; ++nt)
        b[nt] = *reinterpret_cast<const short8*>(
            &Bs[wn * 64 + nt * 16 + (lane & 15)][kc * 32 + (lane >> 4) * 8]);
      __builtin_amdgcn_s_setprio(1);
      #pragma unroll
      for (int mt = 0; mt < 4; ++mt)
        #pragma unroll
        for (int nt = 0; nt < 4; ++nt)
          acc[mt][nt] = MFMA16(a[mt], b[nt], acc[mt][nt]);
      __builtin_amdgcn_s_setprio(0);
    }
    __syncthreads();
  }
  #pragma unroll
  for (int nt = 0; nt < 4; ++nt) {
    int col = n0 + wn * 64 + nt * 16 + (lane & 15);
    float bval = bias[col];
    #pragma unroll
    for (int mt = 0; mt < 4; ++mt) {
      int rbase = m0 + wm * 64 + mt * 16 + ((lane >> 4) << 2);
      #pragma unroll
      for (int r = 0; r < 4; ++r)
        C[(size_t)(rbase + r) * 1024 + col] = f2b(acc[mt][nt][r] + bval);
    }
  }
}

// ---------- flash attention: 8 waves x 32q (Q-tile 256), static-max, 2 barriers/tile ----------
#define PACK8(S, j0, OUT) {                                        \
    unsigned A_ = cvtpk(S[(j0)+0], S[(j0)+1]);                     \
    unsigned B_ = cvtpk(S[(j0)+4], S[(j0)+5]);                     \
    unsigned C_ = cvtpk(S[(j0)+2], S[(j0)+3]);                     \
    unsigned D_ = cvtpk(S[(j0)+6], S[(j0)+7]);                     \
    pl32swap(A_, B_); pl32swap(C_, D_);                            \
    FW f_; f_.u[0] = A_; f_.u[1] = C_; f_.u[2] = B_; f_.u[3] = D_; \
    OUT = f_.s; }

__global__ __launch_bounds__(512, 2) void attn8(
    const unsigned short* __restrict__ qg,
    const unsigned short* __restrict__ kg,
    const unsigned short* __restrict__ vtg,
    const int* __restrict__ midx,
    unsigned short* __restrict__ ctx)
{
  __shared__ short Ks[2][64 * 64];
  __shared__ short Vs[2][64 * 64];
  const int tid = threadIdx.x, w = tid >> 6, lane = tid & 63;
  // XCD swizzle: 512 blocks; 64 consecutive swzb per XCD -> 8 bh per XCD
  const int flat = blockIdx.y * 8 + blockIdx.x;
  const int swzb = (flat & 7) * 64 + (flat >> 3);
  const int qt = swzb & 7, bh = swzb >> 3;
  const int q0 = qt * 256;
  const int lo5 = lane & 31, hi = lane >> 5;
  const int i0 = midx[0], i1 = midx[1], i2 = midx[2];

  // Q fragments (B-operand), pre-scaled by 0.125*log2e; wave owns q-rows [w*32, w*32+32)
  const int qrow = q0 + w * 32 + lo5;
  const unsigned short* qp = qg + ((size_t)bh * 2048 + qrow) * 64 + hi * 8;
  short8 qf[4];
  #pragma unroll
  for (int ds = 0; ds < 4; ++ds) qf[ds] = ld8(qp + ds * 16);

  f32x16 oacc0, oacc1, lacc;
  #pragma unroll
  for (int r = 0; r < 16; ++r) { oacc0[r] = 0.f; oacc1[r] = 0.f; lacc[r] = 0.f; }

  // staging: thread tid covers row tid>>3, col chunk tid&7 (pre-swizzled source)
  const int srow = tid >> 3;
  const int swzoff = (((tid & 7) ^ (srow & 7))) * 8;
  const unsigned short* kp = kg + ((size_t)bh * 2048 + srow) * 64 + swzoff;
  const unsigned short* vp = vtg + ((size_t)bh * 64 + srow) * 2048 + swzoff;

#define STAGE8(bufi, tt) do {                                                  \
    __builtin_amdgcn_global_load_lds((const GAS void*)(kp + (size_t)(tt) * 4096), \
        (LAS void*)&Ks[bufi][w * 512], 16, 0, 0);                              \
    __builtin_amdgcn_global_load_lds((const GAS void*)(vp + (tt) * 64),        \
        (LAS void*)&Vs[bufi][w * 512], 16, 0, 0);                              \
  } while (0)

  // depth-2 prologue: tiles 0,1 staged (4 loads/wave outstanding)
  STAGE8(0, 0);
  STAGE8(1, 1);

  for (int t = 0; t < 32; ++t) {
    const int buf = t & 1;
    // entry: tile t's K+V (2 oldest) drained; tile t+1's 2 stay in flight
    if (t < 31) { asm volatile("s_waitcnt vmcnt(2)" ::: "memory"); }
    else        { asm volatile("s_waitcnt vmcnt(0)" ::: "memory"); }
    __builtin_amdgcn_sched_barrier(0);
    __builtin_amdgcn_s_barrier();          // all waves' tile-t data resident
    __builtin_amdgcn_sched_barrier(0);

    // ---- K fragments -> regs ----
    short8 kf[8];
    #pragma unroll
    for (int ds = 0; ds < 4; ++ds) {
      int cw = ds * 2 + hi;
      kf[2 * ds] = *reinterpret_cast<const short8*>(
          &Ks[buf][lo5 * 64 + ((cw ^ (lo5 & 7)) * 8)]);
      kf[2 * ds + 1] = *reinterpret_cast<const short8*>(
          &Ks[buf][(32 + lo5) * 64 + ((cw ^ (lo5 & 7)) * 8)]);
    }

    // ---- S^T = K . Q^T ----
    f32x16 s0, s1;
    #pragma unroll
    for (int r = 0; r < 16; ++r) { s0[r] = 0.f; s1[r] = 0.f; }
    __builtin_amdgcn_s_setprio(1);
    #pragma unroll
    for (int ds = 0; ds < 4; ++ds) {
      s0 = MFMA32(kf[2 * ds], qf[ds], s0);
      s1 = MFMA32(kf[2 * ds + 1], qf[ds], s1);
    }
    __builtin_amdgcn_s_setprio(0);

    // ---- V fragments -> regs (latency hidden under softmax) ----
    short8 vf[8];
    #pragma unroll
    for (int ks = 0; ks < 4; ++ks) {
      int cw = ks * 2 + hi;
      vf[2 * ks] = *reinterpret_cast<const short8*>(
          &Vs[buf][lo5 * 64 + ((cw ^ (lo5 & 7)) * 8)]);
      vf[2 * ks + 1] = *reinterpret_cast<const short8*>(
          &Vs[buf][(32 + lo5) * 64 + ((cw ^ (lo5 & 7)) * 8)]);
    }

    // ---- static-max softmax: p = 2^s (scale folded into Q) ----
    #pragma unroll
    for (int r = 0; r < 16; ++r) s0[r] = fexp2(s0[r]);
    #pragma unroll
    for (int r = 0; r < 16; ++r) s1[r] = fexp2(s1[r]);

    int t64 = t * 64;
    bool tm = ((unsigned)(i0 - t64) < 64u) | ((unsigned)(i1 - t64) < 64u) |
              ((unsigned)(i2 - t64) < 64u);
    if (tm) {
      #pragma unroll
      for (int r = 0; r < 16; ++r) {
        int kg0 = t64 + (r & 3) + 8 * (r >> 2) + 4 * hi;
        int kg1 = kg0 + 32;
        if (kg0 == i0 || kg0 == i1 || kg0 == i2) s0[r] = 0.f;
        if (kg1 == i0 || kg1 == i1 || kg1 == i2) s1[r] = 0.f;
      }
    }

    #pragma unroll
    for (int r = 0; r < 16; ++r) lacc[r] += s0[r] + s1[r];

    short8 pa[4];
    PACK8(s0, 0, pa[0]); PACK8(s0, 8, pa[1]);
    PACK8(s1, 0, pa[2]); PACK8(s1, 8, pa[3]);

    // ---- release barrier: all waves done reading Ks/Vs[buf] ----
    asm volatile("s_waitcnt lgkmcnt(0)" ::: "memory");
    __builtin_amdgcn_sched_barrier(0);
    __builtin_amdgcn_s_barrier();
    __builtin_amdgcn_sched_barrier(0);
    if (t < 30) STAGE8(buf, t + 2);        // refill buf with tile t+2

    // ---- O += P . V ----
    __builtin_amdgcn_s_setprio(1);
    #pragma unroll
    for (int ks = 0; ks < 4; ++ks) {
      oacc0 = MFMA32(pa[ks], vf[2 * ks], oacc0);
      oacc1 = MFMA32(pa[ks], vf[2 * ks + 1], oacc1);
    }
    __builtin_amdgcn_s_setprio(0);
  }

  // ---- epilogue: ctx = O / lsum, token-major ----
  float lsum = 0.f;
  #pragma unroll
  for (int r = 0; r < 16; ++r) lsum += lacc[r];
  lsum = xhalf_sum(lsum);
  const int bb = bh >> 4, hh = bh & 15;
  float rinv = 1.0f / lsum;
  #pragma unroll
  for (int r = 0; r < 16; ++r) {
    int row = (r & 3) + 8 * (r >> 2) + 4 * hi;
    float rv = __int_as_float(__builtin_amdgcn_ds_bpermute(
        (row + (lane & 32)) * 4, __float_as_int(rinv)));
    int qr = q0 + w * 32 + row;
    size_t base = (((size_t)(bb * 2048 + qr)) * 16 + hh) * 64;
    ctx[base + lo5]      = f2b(oacc0[r] * rv);
    ctx[base + 32 + lo5] = f2b(oacc1[r] * rv);
  }
}

// ---------- residual + LayerNorm ----------
__global__ __launch_bounds__(256) void resid_ln(
    const float* __restrict__ x, const unsigned short* __restrict__ ao,
    const float* __restrict__ gamma, const float* __restrict__ beta,
    float* __restrict__ out)
{
  const int row = blockIdx.x, t = threadIdx.x;
  const size_t base = (size_t)row * 1024;
  float4 xv = reinterpret_cast<const float4*>(x + base)[t];
  ushort4 av = reinterpret_cast<const ushort4*>(ao + base)[t];
  float y[4] = {xv.x + b2f(av.x), xv.y + b2f(av.y), xv.z + b2f(av.z), xv.w + b2f(av.w)};
  float sum = y[0] + y[1] + y[2] + y[3];
  float sq = y[0] * y[0] + y[1] * y[1] + y[2] * y[2] + y[3] * y[3];
  #pragma unroll
  for (int off = 1; off < 64; off <<= 1) {
    sum += __shfl_xor(sum, off);
    sq += __shfl_xor(sq, off);
  }
  __shared__ float s1[4], s2[4];
  int w = t >> 6, lane = t & 63;
  if (lane == 0) { s1[w] = sum; s2[w] = sq; }
  __syncthreads();
  sum = s1[0] + s1[1] + s1[2] + s1[3];
  sq = s2[0] + s2[1] + s2[2] + s2[3];
  float mu = sum * (1.f / 1024.f);
  float var = sq * (1.f / 1024.f) - mu * mu;
  float inv = rsqrtf(var + 1e-5f);
  float4 gv = reinterpret_cast<const float4*>(gamma)[t];
  float4 bv = reinterpret_cast<const float4*>(beta)[t];
  float4 o;
  o.x = (y[0] - mu) * inv * gv.x + bv.x;
  o.y = (y[1] - mu) * inv * gv.y + bv.y;
  o.z = (y[2] - mu) * inv * gv.z + bv.z;
  o.w = (y[3] - mu) * inv * gv.w + bv.w;
  reinterpret_cast<float4*>(out + base)[t] = o;
}

// ---------- launch ----------
extern "C" void kernel_launch(void* const* d_in, const int* in_sizes, int n_in,
                              void* d_out, int out_size, void* d_ws, size_t ws_size,
                              hipStream_t stream)
{
  const float* x     = (const float*)d_in[0];
  const float* band  = (const float*)d_in[1];
  const float* Wq    = (const float*)d_in[2];
  const float* bq    = (const float*)d_in[3];
  const float* Wk    = (const float*)d_in[4];
  const float* bk    = (const float*)d_in[5];
  const float* Wv    = (const float*)d_in[6];
  const float* bv    = (const float*)d_in[7];
  const float* Wo    = (const float*)d_in[8];
  const float* bo    = (const float*)d_in[9];
  const float* gamma = (const float*)d_in[10];
  const float* beta  = (const float*)d_in[11];
  float* out = (float*)d_out;

  char* ws = (char*)d_ws;
  int*            idxw  = (int*)(ws);                          // 16 B
  unsigned short* xb    = (unsigned short*)(ws + 4096);        // 16 MB
  unsigned short* Wqkvb = (unsigned short*)(ws + 16781312);    // 6 MB [3072][1024]
  unsigned short* Wob   = (unsigned short*)(ws + 23072768);    // 2 MB
  unsigned short* qb    = (unsigned short*)(ws + 25169920);    // head-major, pre-scaled
  unsigned short* kb    = (unsigned short*)(ws + 41947136);    // head-major
  unsigned short* ctxb  = (unsigned short*)(ws + 58724352);    // token-major ctx
  unsigned short* vtb   = (unsigned short*)(ws + 75501568);    // V^T [BH][64][L]
  unsigned short* aob   = qb;                                  // reuse after attn

  const float QSCALE = 0.125f * 1.44269504f;  // softmax scale + log2(e) folded into Q

  cvt_topk<<<12289, 256, 0, stream>>>(x, Wq, Wk, Wv, Wo, band, xb, Wqkvb, Wob, idxw);

  gemm_qkv256<<<dim3(32, 12), 512, 0, stream>>>(xb, Wqkvb, bq, bk, bv,
                                                qb, kb, vtb, QSCALE);

  attn8<<<dim3(8, 64), 512, 0, stream>>>(qb, kb, vtb, idxw, ctxb);

  gemm_wo<<<dim3(64, 8), 256, 0, stream>>>(ctxb, Wob, bo, aob);

  resid_ln<<<8192, 256, 0, stream>>>(x, aob, gamma, beta, out);
}